// Round 8
// baseline (23445.468 us; speedup 1.0000x reference)
//
#include <hip/hip_runtime.h>

// ---------------------------------------------------------------------------
// 2-layer ReLU RNN, B=64 T=2048 IN=256 H=512 C=128. fp32 inputs (runtime
// dtype detect kept), output dtype matches input.
//
// Round-13: self-contained-WG architecture (h in LDS, zero exchange on the
// recurrent chain), re-dimensioned to fit the register file:
//  - Recurrent WGs are 256 thr / 4 waves -> 1 wave/SIMD -> 512-VGPR cap
//    (rounds 11/12 used 8 waves -> 256 cap -> W spilled, 9-11us/step).
//    Wave owns 128 cols: 96 in registers (Bf[6][16] = 384 VGPR), 32 via
//    LDS WL (128 cols x 512 = 128KB, filled once; depth-2 prefetch ring).
//  - PROJ WGs (16): 128 cols each, W all-register (Bf[2][16]).
//  - hexZ uses LSB tags (tag nibble in the 4 f16 LSBs; z is signed so sign
//    bits are not free): 4 f16/u64 -> L1REC holds only 8 u64 in flight.
//    <=1 ulp noise on z (~1e-3, threshold 5.9e-3). hexZ is re-initialized
//    to tag-15 each launch (poison/replay-alias audit holds). hex0 keeps
//    sign tags (h0 >= 0 post-relu).
// Flow control (unchanged): hex0/hexZ 8-rings, LAG=7; progP gates L0's
// hex0 reuse (PROJ consumed t-7); progL gates PROJ's hexZ reuse (L1REC
// consumed t-7). Acyclic; all spins guard-limited -> no hangs.
// Grid = 24 x 256: bid 0-3 L0(r), 4-7 L1REC(r), 8-23 PROJ(r,q).
// ---------------------------------------------------------------------------

typedef unsigned short u16;
typedef unsigned int u32;
typedef unsigned long long u64;
typedef _Float16 f16;
typedef _Float16 half8 __attribute__((ext_vector_type(8)));
typedef float float4v __attribute__((ext_vector_type(4)));

#define T_LEN 2048
#define H_DIM 512
#define B_SZ 64
#define SGN 0x8000800080008000ull
#define VMASK 0x7fff7fff7fff7fffull
#define ZMASK 0x0001000100010001ull
#define SPIN_LIM (1 << 15)
#define LAG 7

__device__ __forceinline__ float bf2f(u16 u) {
    union { u32 i; float f; } v; v.i = ((u32)u) << 16; return v.f;
}
__device__ __forceinline__ u16 f2bf(float f) {
    u32 x = __float_as_uint(f);
    u32 r = (x + 0x7fffu + ((x >> 16) & 1u)) >> 16;
    return (u16)r;
}
__device__ __forceinline__ float loadf(const void* p, size_t i, int dt) {
    return dt ? ((const float*)p)[i] : bf2f(((const u16*)p)[i]);
}
__device__ __forceinline__ half8 cvt8_bf16(uint4 v) {
    half8 h;
    h[0] = (f16)bf2f((u16)(v.x & 0xffff)); h[1] = (f16)bf2f((u16)(v.x >> 16));
    h[2] = (f16)bf2f((u16)(v.y & 0xffff)); h[3] = (f16)bf2f((u16)(v.y >> 16));
    h[4] = (f16)bf2f((u16)(v.z & 0xffff)); h[5] = (f16)bf2f((u16)(v.z >> 16));
    h[6] = (f16)bf2f((u16)(v.w & 0xffff)); h[7] = (f16)bf2f((u16)(v.w >> 16));
    return h;
}
// sign-bit tag (hex0): 4-bit nibble t&15 in the 4 f16 sign bits.
__device__ __forceinline__ u64 tagmask(int t) {
    return ((t & 1) ? 0x0000000000008000ull : 0ull) |
           ((t & 2) ? 0x0000000080000000ull : 0ull) |
           ((t & 4) ? 0x0000800000000000ull : 0ull) |
           ((t & 8) ? 0x8000000000000000ull : 0ull);
}
// LSB tag (hexZ): 4-bit nibble t&15 in the 4 f16 LSBs.
__device__ __forceinline__ u64 ztag(int t) {
    return ((u64)(t & 1)) | ((u64)((t >> 1) & 1) << 16) |
           ((u64)((t >> 2) & 1) << 32) | ((u64)((t >> 3) & 1) << 48);
}
__device__ __forceinline__ u64 aload(u64* p) {
    return __hip_atomic_load(p, __ATOMIC_RELAXED, __HIP_MEMORY_SCOPE_AGENT);
}
__device__ __forceinline__ void astore(u64* p, u64 v) {
    __hip_atomic_store(p, v, __ATOMIC_RELAXED, __HIP_MEMORY_SCOPE_AGENT);
}
__device__ __forceinline__ u32 aload32(u32* p) {
    return __hip_atomic_load(p, __ATOMIC_RELAXED, __HIP_MEMORY_SCOPE_AGENT);
}
__device__ __forceinline__ void astore32(u32* p, u32 v) {
    __hip_atomic_store(p, v, __ATOMIC_RELAXED, __HIP_MEMORY_SCOPE_AGENT);
}
__device__ __forceinline__ float f16u(u16 b) {
    union { u16 u; f16 h; } c; c.u = b; return (float)c.h;
}

// --------------------------- dtype detection -------------------------------
__global__ void detect_kernel(const u16* __restrict__ xr, int* __restrict__ dtf,
                              u32* __restrict__ progP, u32* __restrict__ progL) {
    int lane = threadIdx.x;
    u16 u0 = xr[(lane * 2 + 0) * 2];
    u16 u1 = xr[(lane * 2 + 1) * 2];
    int e0 = (u0 >> 7) & 0xff, e1 = (u1 >> 7) & 0xff;
    int c0 = (e0 >= 0x60 && e0 <= 0x8f) ? 1 : 0;
    int c1 = (e1 >= 0x60 && e1 <= 0x8f) ? 1 : 0;
    int tot = __popcll(__ballot(c0)) + __popcll(__ballot(c1));
    if (lane == 0) *dtf = (tot >= 96) ? 0 : 1;   // 0 = bf16, 1 = fp32
    progP[lane] = 0;
    progL[lane] = 0;
}

// --------------------------- prep kernels ----------------------------------
__global__ void cvt_w_kernel(const void* __restrict__ in, f16* __restrict__ out,
                             int n, const int* __restrict__ dtf) {
    int dt = *dtf;
    for (int i = blockIdx.x * blockDim.x + threadIdx.x; i < n; i += gridDim.x * blockDim.x)
        out[i] = (f16)loadf(in, i, dt);
}

__global__ void bias_kernel(const void* __restrict__ bi, const void* __restrict__ bh,
                            float* __restrict__ bias, const int* __restrict__ dtf) {
    int dt = *dtf;
    int i = blockIdx.x * blockDim.x + threadIdx.x;
    if (i < H_DIM) bias[i] = loadf(bi, i, dt) + loadf(bh, i, dt);
}

__global__ void fcb_kernel(const void* __restrict__ in, float* __restrict__ out,
                           const int* __restrict__ dtf) {
    int i = threadIdx.x;
    if (i < 128) out[i] = loadf(in, i, *dtf);
}

__global__ void initz_kernel(u64* __restrict__ hexZ) {
    int i = blockIdx.x * blockDim.x + threadIdx.x;   // 65536 threads
    hexZ[i] = 0x0001000100010001ull;                 // LSB tag 15
}

// --------------------------- tiled MFMA GEMM -------------------------------
template<int RAW>
__global__ __launch_bounds__(256)
void gemm_tiled(const void* __restrict__ Araw, const f16* __restrict__ Bw,
                const float* __restrict__ bias, f16* __restrict__ C,
                int lgTc, int t_off, int K, const int* __restrict__ dtf)
{
    __shared__ f16 As[64][40];
    __shared__ f16 Bs[64][40];
    const int dt = RAW ? *dtf : 0;
    const int m0 = blockIdx.x * 64, n0 = blockIdx.y * 64;
    const int tid = threadIdx.x;
    const int wv = tid >> 6, lane = tid & 63;
    const int lr = lane & 15, quad = lane >> 4;
    const int srow = tid >> 2, skq = tid & 3;

    float4v acc[4] = {{0.f,0.f,0.f,0.f},{0.f,0.f,0.f,0.f},{0.f,0.f,0.f,0.f},{0.f,0.f,0.f,0.f}};

    size_t arow;
    {
        int ml = m0 + srow;
        if (RAW) {
            int b = ml >> lgTc, tt = ml & ((1 << lgTc) - 1);
            arow = (size_t)b * T_LEN + t_off + tt;
        } else arow = (size_t)ml;
    }
    const f16* pb = Bw + (size_t)(n0 + srow) * K + skq * 8;

    for (int k0 = 0; k0 < K; k0 += 32) {
        half8 av;
        if (RAW) {
            if (dt) {
                const float* ap = (const float*)Araw + arow * K + k0 + skq * 8;
                float4v f0 = *(const float4v*)ap;
                float4v f1 = *(const float4v*)(ap + 4);
                av[0]=(f16)f0[0]; av[1]=(f16)f0[1]; av[2]=(f16)f0[2]; av[3]=(f16)f0[3];
                av[4]=(f16)f1[0]; av[5]=(f16)f1[1]; av[6]=(f16)f1[2]; av[7]=(f16)f1[3];
            } else {
                av = cvt8_bf16(*(const uint4*)((const u16*)Araw + arow * K + k0 + skq * 8));
            }
        } else {
            av = *(const half8*)((const f16*)Araw + arow * K + k0 + skq * 8);
        }
        half8 bv = *(const half8*)(pb + k0);
        __syncthreads();
        *(half8*)&As[srow][skq * 8] = av;
        *(half8*)&Bs[srow][skq * 8] = bv;
        __syncthreads();
        half8 bf = *(const half8*)&Bs[wv * 16 + lr][quad * 8];
#pragma unroll
        for (int mt = 0; mt < 4; ++mt) {
            half8 af = *(const half8*)&As[mt * 16 + lr][quad * 8];
            acc[mt] = __builtin_amdgcn_mfma_f32_16x16x32_f16(af, bf, acc[mt], 0, 0, 0);
        }
    }
    const int n = n0 + wv * 16 + lr;
    const float bval = bias[n];
#pragma unroll
    for (int mt = 0; mt < 4; ++mt) {
#pragma unroll
        for (int i = 0; i < 4; ++i) {
            int m = m0 + mt * 16 + quad * 4 + i;
            C[(size_t)m * H_DIM + n] = (f16)(acc[mt][i] + bval);
        }
    }
}

// --------------------------- 3-role scan -----------------------------------
// grid = 24 x 256 (4 waves, 1 wave/SIMD -> 512-VGPR budget, 1 WG/CU).
// hex0 [8][64][128] u64 row-major (sign tags). hexZ [8][4][2048] u64
// col-major (u64 = rows quad*4..+3 of one col; LSB tags).
// progP[r*4+q]: PROJ(r,q) consumed h0_t -> t+1. progL[r]: L1REC consumed z_t.
__global__ __launch_bounds__(256, 1)
void rnn_scan3(const f16* __restrict__ pre0,    // [B,Tc,H] chunk-local
               const f16* __restrict__ Whh0,    // [H,H] fp16
               const f16* __restrict__ Wih1,    // [H,H] fp16
               const f16* __restrict__ Whh1,    // [H,H] fp16
               const float* __restrict__ bias1, // [H] fp32
               u64* __restrict__ hex0,          // [8][64][128]
               u64* __restrict__ hexZ,          // [8][4][2048]
               f16* __restrict__ hc0,           // [B,H] layer-0 carry
               f16* __restrict__ hc1,           // [B,H] layer-1 carry
               u32* __restrict__ progP,         // [16 used]
               u32* __restrict__ progL,         // [4 used]
               int t0, int Tc,
               float* __restrict__ h_last)      // [B,H] fp32
{
    __shared__ f16 stage[16 * 512];    // 16KB: h (rec) / sH0 (PROJ)
    __shared__ f16 WL[128 * 512];      // 128KB: LDS W block (rec only)
    const int bid = blockIdx.x;
    const int tid = threadIdx.x;
    const int w = tid >> 6, lane = tid & 63;
    const int lr = lane & 15, quad = lane >> 4;

    if (bid >= 8) {
        // ============================ PROJ ============================
        const int pr = bid - 8;
        const int r = pr >> 2, q = pr & 3;
        const int rows0 = r * 16;
        const int c0p = q * 128 + w * 32;
        half8 Bf[2][16];
#pragma unroll
        for (int j = 0; j < 2; ++j)
#pragma unroll
            for (int kc = 0; kc < 16; ++kc)
                Bf[j][kc] = *(const half8*)(Wih1 + (size_t)(c0p + j * 16 + lr) * H_DIM
                                            + kc * 32 + quad * 8);
        float bvv[2] = { bias1[c0p + lr], bias1[c0p + 16 + lr] };
        const int rrow = tid >> 4;           // 16 rows x 16 thr
        const int rc8 = (tid & 15) * 8;      // 8 u64-cols per thread
        const int z0 = (c0p + lr) * 4 + quad;

        u64 vv[8];
        {
            u64* src = hex0 + ((size_t)(t0 & 7) * 64 + rows0 + rrow) * 128;
#pragma unroll
            for (int k = 0; k < 8; ++k) vv[k] = aload(&src[rc8 + k]);
        }

        for (int tt = 0; tt < Tc; ++tt) {
            const int t = t0 + tt;
            const int nb = t & 7;
            const u64 em = tagmask(t);
            const int need = t - LAG;
            const u32 want = (u32)(need + 1);

            u32 plv = 0xffffffffu;
            if (need >= 0) plv = aload32(&progL[r]);   // early poll

            // validate h0_t (sign tags) -> stage (sH0)
            {
                u64* src = hex0 + ((size_t)nb * 64 + rows0 + rrow) * 128;
                int pend = 0;
#pragma unroll
                for (int k = 0; k < 8; ++k)
                    if ((vv[k] & SGN) != em) pend |= 1 << k;
                int guard = 0;
                while (pend && guard < SPIN_LIM) {
#pragma unroll
                    for (int k = 0; k < 8; ++k)
                        if (pend & (1 << k)) vv[k] = aload(&src[rc8 + k]);
#pragma unroll
                    for (int k = 0; k < 8; ++k)
                        if ((pend & (1 << k)) && ((vv[k] & SGN) == em))
                            pend &= ~(1 << k);
                    ++guard;
                }
#pragma unroll
                for (int k = 0; k < 8; ++k) {
                    int cu = rc8 + k;
                    *(u64*)&stage[rrow * 512 + ((cu >> 1) ^ (rrow & 7)) * 8 + (cu & 1) * 4] =
                        vv[k] & VMASK;
                }
            }
            __syncthreads();   // sH0 ready; all hex0[t] reads done
            if (tid == 0) astore32(&progP[r * 4 + q], (u32)(t + 1));

            float4v acc0 = {0.f,0.f,0.f,0.f}, acc1 = {0.f,0.f,0.f,0.f};
#pragma unroll
            for (int kc = 0; kc < 16; ++kc) {
                half8 a = *(const half8*)&stage[lr * 512 + (((kc * 4 + quad) ^ (lr & 7)) * 8)];
                acc0 = __builtin_amdgcn_mfma_f32_16x16x32_f16(a, Bf[0][kc], acc0, 0, 0, 0);
                acc1 = __builtin_amdgcn_mfma_f32_16x16x32_f16(a, Bf[1][kc], acc1, 0, 0, 0);
            }

            // pack z with LSB tags (u64 = rows quad*4..+3 of one col)
            const u64 ez = ztag(t);
            u64 zw[2];
#pragma unroll
            for (int j = 0; j < 2; ++j) {
                const float4v& a = j ? acc1 : acc0;
                u64 wp = 0;
#pragma unroll
                for (int i = 0; i < 4; ++i) {
                    union { f16 h; u16 u; } c;
                    c.h = (f16)(a[i] + bvv[j]);
                    wp |= ((u64)(c.u & 0xFFFEu)) << (16 * i);
                }
                zw[j] = wp | ez;
            }

            // throttle: publishing z_t destroys z_{t-8}; progL>=t-6 certifies.
            if (need >= 0) {
                int g = 0;
                while (plv < want && g < SPIN_LIM) { plv = aload32(&progL[r]); ++g; }
            }
            {
                u64* dz = hexZ + ((size_t)nb * 4 + r) * 2048;
                astore(&dz[z0], zw[0]);
                astore(&dz[z0 + 64], zw[1]);
            }
            if (tt + 1 < Tc) {
                u64* srcn = hex0 + ((size_t)((t + 1) & 7) * 64 + rows0 + rrow) * 128;
#pragma unroll
                for (int k = 0; k < 8; ++k) vv[k] = aload(&srcn[rc8 + k]);
            }
            __syncthreads();   // protect sH0 rewrite next iteration
        }
        return;
    }

    // ========================= L0 / L1REC =========================
    const int role = bid >> 2;            // 0 = L0, 1 = L1REC
    const int r = bid & 3;
    const int rows0 = r * 16;
    const int c0w = w * 128;              // wave's 128 output cols
    const f16* Wrec = role ? Whh1 : Whh0;
    f16* hcar = role ? hc1 : hc0;

    // W: j-blocks 0..5 in registers (384 VGPR), j-blocks 6,7 in LDS WL.
    half8 Bf[6][16];
#pragma unroll
    for (int j = 0; j < 6; ++j)
#pragma unroll
        for (int kc = 0; kc < 16; ++kc)
            Bf[j][kc] = *(const half8*)(Wrec + (size_t)(c0w + j * 16 + lr) * H_DIM
                                        + kc * 32 + quad * 8);

    // Fill WL: LDS col cl (0..127) = global col (cl>>5)*128 + 96 + (cl&31).
    // 128 cols x 64 granules(16B) = 8192 granules / 256 thr = 32 each.
    {
        for (int it = 0; it < 32; ++it) {
            int idx = tid * 32 + it;
            int cl = idx >> 6, g = idx & 63;
            int gcol = (cl >> 5) * 128 + 96 + (cl & 31);
            *(uint4*)&WL[cl * 512 + ((g ^ (cl & 7)) * 8)] =
                *(const uint4*)(Wrec + (size_t)gcol * H_DIM + g * 8);
        }
    }

    if (t0 > 0) {
        int row = tid >> 4, g0 = (tid & 15) * 4;
#pragma unroll
        for (int gq = 0; gq < 4; ++gq) {
            int g = g0 + gq;
            *(uint4*)&stage[row * 512 + ((g ^ (row & 7)) * 8)] =
                *(const uint4*)(hcar + (size_t)(rows0 + row) * H_DIM + g * 8);
        }
    }
    __syncthreads();

    const int cl6 = w * 32 + lr, cl7 = cl6 + 16;
    const int b6 = cl6 * 512, x6 = cl6 & 7;
    const int b7 = cl7 * 512, x7 = cl7 & 7;
    const int z0 = (c0w + lr) * 4 + quad;          // L1REC hexZ base (+j*64)
    const int prow = tid >> 4, pc8 = (tid & 15) * 8;  // L0 publish: 8 u64

    u64 vvz[8];                            // L1REC in-flight z words
    if (role) {
        u64* zb = hexZ + ((size_t)(t0 & 7) * 4 + r) * 2048;
#pragma unroll
        for (int k = 0; k < 8; ++k) vvz[k] = aload(&zb[z0 + k * 64]);
    }
    f16 pvh[8][4];                         // L0 pre_t (pipelined)
    if (!role) {
#pragma unroll
        for (int j = 0; j < 8; ++j)
#pragma unroll
            for (int i = 0; i < 4; ++i)
                pvh[j][i] = pre0[((size_t)(rows0 + quad * 4 + i) * Tc + 0) * H_DIM
                                 + c0w + j * 16 + lr];
    }

    for (int tt = 0; tt < Tc; ++tt) {
        const int t = t0 + tt;
        const int nb = t & 7;
        const u64 em = tagmask(t);
        const int need = t - LAG;
        const u32 want = (u32)(need + 1);

        u32 ppv = 0xffffffffu;
        if (!role && need >= 0 && lane < 4)
            ppv = aload32(&progP[r * 4 + lane]);       // early poll

        // [A] MFMA: h_{t-1} (stage) x [Bf regs | WL block], K=512, 8 j-blocks.
        float4v acc[8] = {{0.f,0.f,0.f,0.f},{0.f,0.f,0.f,0.f},{0.f,0.f,0.f,0.f},
                          {0.f,0.f,0.f,0.f},{0.f,0.f,0.f,0.f},{0.f,0.f,0.f,0.f},
                          {0.f,0.f,0.f,0.f},{0.f,0.f,0.f,0.f}};
        if (t > 0) {
            half8 wl6[2], wl7[2];
            wl6[0] = *(const half8*)&WL[b6 + ((quad ^ x6) * 8)];
            wl7[0] = *(const half8*)&WL[b7 + ((quad ^ x7) * 8)];
            wl6[1] = *(const half8*)&WL[b6 + (((4 + quad) ^ x6) * 8)];
            wl7[1] = *(const half8*)&WL[b7 + (((4 + quad) ^ x7) * 8)];
#pragma unroll
            for (int kc = 0; kc < 16; ++kc) {
                half8 a = *(const half8*)&stage[lr * 512 + (((kc * 4 + quad) ^ (lr & 7)) * 8)];
                acc[0] = __builtin_amdgcn_mfma_f32_16x16x32_f16(a, Bf[0][kc], acc[0], 0, 0, 0);
                acc[1] = __builtin_amdgcn_mfma_f32_16x16x32_f16(a, Bf[1][kc], acc[1], 0, 0, 0);
                acc[2] = __builtin_amdgcn_mfma_f32_16x16x32_f16(a, Bf[2][kc], acc[2], 0, 0, 0);
                acc[3] = __builtin_amdgcn_mfma_f32_16x16x32_f16(a, Bf[3][kc], acc[3], 0, 0, 0);
                acc[4] = __builtin_amdgcn_mfma_f32_16x16x32_f16(a, Bf[4][kc], acc[4], 0, 0, 0);
                acc[5] = __builtin_amdgcn_mfma_f32_16x16x32_f16(a, Bf[5][kc], acc[5], 0, 0, 0);
                acc[6] = __builtin_amdgcn_mfma_f32_16x16x32_f16(a, wl6[kc & 1], acc[6], 0, 0, 0);
                acc[7] = __builtin_amdgcn_mfma_f32_16x16x32_f16(a, wl7[kc & 1], acc[7], 0, 0, 0);
                if (kc + 2 < 16) {
                    wl6[kc & 1] = *(const half8*)&WL[b6 + ((((kc + 2) * 4 + quad) ^ x6) * 8)];
                    wl7[kc & 1] = *(const half8*)&WL[b7 + ((((kc + 2) * 4 + quad) ^ x7) * 8)];
                }
            }
        }

        // L1REC: validate z_t (LSB tags; prefetched -> usually hit).
        if (role) {
            u64* zb = hexZ + ((size_t)nb * 4 + r) * 2048;
            const u64 ez = ztag(t);
            int pend = 0;
#pragma unroll
            for (int k = 0; k < 8; ++k)
                if ((vvz[k] & ZMASK) != ez) pend |= 1 << k;
            int guard = 0;
            while (pend && guard < SPIN_LIM) {
#pragma unroll
                for (int k = 0; k < 8; ++k)
                    if (pend & (1 << k)) vvz[k] = aload(&zb[z0 + k * 64]);
#pragma unroll
                for (int k = 0; k < 8; ++k)
                    if ((pend & (1 << k)) && ((vvz[k] & ZMASK) == ez))
                        pend &= ~(1 << k);
                ++guard;
            }
        }
        __syncthreads();   // stage reads + z reads complete
        if (role && tid == 0) astore32(&progL[r], (u32)(t + 1));

        // [B] h_t = relu(acc + pv) -> stage (own cols).
        f16 hv[8][4];
#pragma unroll
        for (int j = 0; j < 8; ++j) {
#pragma unroll
            for (int i = 0; i < 4; ++i) {
                float pvv;
                if (role) pvv = f16u((u16)((vvz[j] >> (16 * i)) & 0xFFFEu));
                else      pvv = (float)pvh[j][i];
                float hval = fmaxf(acc[j][i] + pvv, 0.f);
                hv[j][i] = (f16)hval;
                int row = quad * 4 + i, lc = c0w + j * 16 + lr;
                stage[row * 512 + ((lc >> 3) ^ (row & 7)) * 8 + (lc & 7)] = hv[j][i];
            }
        }
        if (role && h_last && t == T_LEN - 1) {
#pragma unroll
            for (int j = 0; j < 8; ++j)
#pragma unroll
                for (int i = 0; i < 4; ++i)
                    h_last[(size_t)(rows0 + quad * 4 + i) * H_DIM + c0w + j * 16 + lr] =
                        (float)hv[j][i];
        }
        if (tt == Tc - 1) {
#pragma unroll
            for (int j = 0; j < 8; ++j)
#pragma unroll
                for (int i = 0; i < 4; ++i)
                    hcar[(size_t)(rows0 + quad * 4 + i) * H_DIM + c0w + j * 16 + lr] =
                        hv[j][i];
        }
        __syncthreads();   // stage (h_t) complete

        // [C] L0: throttle + publish h0_t; both: prefetch next input.
        if (!role) {
            if (need >= 0) {
                bool ok = __all((lane < 4) ? (ppv >= want) : 1);
                int g = 0;
                while (!ok && g < SPIN_LIM) {
                    if (lane < 4) ppv = aload32(&progP[r * 4 + lane]);
                    ok = __all((lane < 4) ? (ppv >= want) : 1);
                    ++g;
                }
            }
            u64* dst = hex0 + ((size_t)nb * 64 + rows0 + prow) * 128;
#pragma unroll
            for (int k = 0; k < 8; ++k) {
                int cu = pc8 + k;
                u64 v = *(const u64*)&stage[prow * 512 + ((cu >> 1) ^ (prow & 7)) * 8
                                            + (cu & 1) * 4];
                astore(&dst[cu], v | em);
            }
            if (tt + 1 < Tc) {
#pragma unroll
                for (int j = 0; j < 8; ++j)
#pragma unroll
                    for (int i = 0; i < 4; ++i)
                        pvh[j][i] = pre0[((size_t)(rows0 + quad * 4 + i) * Tc + tt + 1)
                                         * H_DIM + c0w + j * 16 + lr];
            }
        } else {
            if (tt + 1 < Tc) {
                u64* zb = hexZ + ((size_t)((t + 1) & 7) * 4 + r) * 2048;
#pragma unroll
                for (int k = 0; k < 8; ++k) vvz[k] = aload(&zb[z0 + k * 64]);
            }
        }
    }
}

// --------------------------- final FC --------------------------------------
__global__ void fc_kernel(const float* __restrict__ hlast, const f16* __restrict__ fcw,
                          const float* __restrict__ fcb, void* __restrict__ out,
                          const int* __restrict__ dtf) {
    int b = blockIdx.x, c = threadIdx.x;
    const float* hrow = hlast + b * H_DIM;
    const f16* wrow = fcw + (size_t)c * H_DIM;
    float s = fcb[c];
    for (int h0 = 0; h0 < H_DIM; h0 += 8) {
        half8 w = *(const half8*)(wrow + h0);
#pragma unroll
        for (int j = 0; j < 8; ++j) s += hrow[h0 + j] * (float)w[j];
    }
    if (*dtf) ((float*)out)[b * 128 + c] = s;
    else      ((u16*)out)[b * 128 + c] = f2bf(s);
}

// --------------------------- launch ----------------------------------------
extern "C" void kernel_launch(void* const* d_in, const int* in_sizes, int n_in,
                              void* d_out, int out_size, void* d_ws, size_t ws_size,
                              hipStream_t stream)
{
    const void* x     = d_in[0];
    const void* W_ih0 = d_in[1];
    const void* W_hh0 = d_in[2];
    const void* b_ih0 = d_in[3];
    const void* b_hh0 = d_in[4];
    const void* W_ih1 = d_in[5];
    const void* W_hh1 = d_in[6];
    const void* b_ih1 = d_in[7];
    const void* b_hh1 = d_in[8];
    const void* fc_w  = d_in[9];
    const void* fc_b  = d_in[10];

    char* ws = (char*)d_ws;
    int*   dtf   = (int*)(ws + 0);            //     64 B
    float* bias0 = (float*)(ws + 4096);       //   2048 B
    float* bias1 = (float*)(ws + 6144);       //   2048 B
    float* fcbf  = (float*)(ws + 8192);       //    512 B
    u32*   progP = (u32*)(ws + 12288);        //    256 B
    u32*   progL = (u32*)(ws + 12544);        //    256 B
    float* hlast = (float*)(ws + 16384);      // 131072 B
    f16*   hc0   = (f16*)(ws + 147456);       //  65536 B
    f16*   hc1   = (f16*)(ws + 212992);       //  65536 B
    u64*   hex0  = (u64*)(ws + 278528);       // 524288 B [8][64][128]
    u64*   hexZ  = (u64*)(ws + 802816);       // 524288 B [8][4][2048]
    f16*   Wih0f = (f16*)(ws + 1327104);      // 262144 B
    f16*   Whh0f = (f16*)(ws + 1589248);      // 524288 B
    f16*   Wih1f = (f16*)(ws + 2113536);      // 524288 B
    f16*   Whh1f = (f16*)(ws + 2637824);      // 524288 B
    f16*   fcwf  = (f16*)(ws + 3162112);      // 131072 B (ends 3293184 < 4MB)

    const size_t misc = 4u << 20;
    int Tc = 128;
    {
        auto need = [&](int tc) {
            return misc + (size_t)B_SZ * (size_t)tc * H_DIM * 2;
        };
        if (ws_size >= need(2048)) Tc = 2048;
        else if (ws_size >= need(1024)) Tc = 1024;
        else if (ws_size >= need(512)) Tc = 512;
        else if (ws_size >= need(256)) Tc = 256;
        else Tc = 128;
    }
    int lgTc = 31 - __builtin_clz((unsigned)Tc);
    f16* bufA = (f16*)(ws + misc);

    detect_kernel<<<dim3(1), dim3(64), 0, stream>>>((const u16*)x, dtf, progP, progL);
    initz_kernel<<<dim3(256), dim3(256), 0, stream>>>(hexZ);
    cvt_w_kernel<<<dim3(512), dim3(256), 0, stream>>>(W_ih0, Wih0f, H_DIM * 256, dtf);
    cvt_w_kernel<<<dim3(1024), dim3(256), 0, stream>>>(W_hh0, Whh0f, H_DIM * H_DIM, dtf);
    cvt_w_kernel<<<dim3(1024), dim3(256), 0, stream>>>(W_ih1, Wih1f, H_DIM * H_DIM, dtf);
    cvt_w_kernel<<<dim3(1024), dim3(256), 0, stream>>>(W_hh1, Whh1f, H_DIM * H_DIM, dtf);
    cvt_w_kernel<<<dim3(256), dim3(256), 0, stream>>>(fc_w, fcwf, 128 * H_DIM, dtf);
    bias_kernel<<<dim3(2), dim3(256), 0, stream>>>(b_ih0, b_hh0, bias0, dtf);
    bias_kernel<<<dim3(2), dim3(256), 0, stream>>>(b_ih1, b_hh1, bias1, dtf);
    fcb_kernel<<<dim3(1), dim3(128), 0, stream>>>(fc_b, fcbf, dtf);

    const int NC = T_LEN / Tc;
    const int mblocks = B_SZ * Tc / 64;
    for (int c = 0; c < NC; ++c) {
        const int t0 = c * Tc;
        gemm_tiled<1><<<dim3(mblocks, 8), 256, 0, stream>>>(
            x, Wih0f, bias0, bufA, lgTc, t0, 256, dtf);
        rnn_scan3<<<dim3(24), dim3(256), 0, stream>>>(
            bufA, Whh0f, Wih1f, Whh1f, bias1, hex0, hexZ, hc0, hc1,
            progP, progL, t0, Tc, hlast);
    }
    fc_kernel<<<dim3(B_SZ), dim3(128), 0, stream>>>(hlast, fcwf, fcbf, d_out, dtf);
}

// Round 10
// 6370.695 us; speedup vs baseline: 3.6802x; 3.6802x over previous
//
#include <hip/hip_runtime.h>

// ---------------------------------------------------------------------------
// 2-layer ReLU RNN, B=64 T=2048 IN=256 H=512 C=128. fp32 inputs (runtime
// dtype detect kept), output dtype matches input.
//
// Round-15: round-10 3-role pipeline (best verified: L0 / L1REC / PROJ,
// 16 WGs each, WG = 16 rows x 128 cols, h exchange via tagged u64 rings)
// with the exchange path re-plumbed for latency:
//  (1) COL-MAJOR u64 exchange (u64 = rows quad*4..+3 of one col) so each
//      compute thread publishes its OWN hv directly after the relu -- no
//      stage round-trip, no barrier before publish. Publisher is ~0.5us
//      earlier -> consumer's prefetched loads usually pass the first tag
//      check (round-10 paid an extra miss round-trip every step).
//  (2) ONE barrier per recurrent step: [A] validate sib(t-1) -> stage[p],
//      barrier, [D] MFMA K=512, [E] relu+throttle+publish+stage-own+issue
//      next sib loads. ([E]-own and next-[A]-sibling stage writes touch
//      disjoint cols of the same buffer; [D] reads the other buffer.)
//  (3) hexZ keeps round-13's PROVEN LSB-tag scheme (z signed); hex0/hex1
//      sign tags (h>=0). Rings 8/2/8, LAG=7, progP/progL gates, all spins
//      guard-limited (no hangs; worst case wrong data -> absmax).
// AGPR/512-reg routes abandoned: 256 arch-VGPR cap proven (r12/r13), manual
// AGPRs collide with compiler accumulator allocation (r14 NaN).
// ---------------------------------------------------------------------------

typedef unsigned short u16;
typedef unsigned int u32;
typedef unsigned long long u64;
typedef _Float16 f16;
typedef _Float16 half8 __attribute__((ext_vector_type(8)));
typedef float float4v __attribute__((ext_vector_type(4)));

#define T_LEN 2048
#define H_DIM 512
#define B_SZ 64
#define SGN 0x8000800080008000ull
#define VMASK 0x7fff7fff7fff7fffull
#define ZMASK 0x0001000100010001ull
#define SPIN_LIM (1 << 15)
#define LAG 7

__device__ __forceinline__ float bf2f(u16 u) {
    union { u32 i; float f; } v; v.i = ((u32)u) << 16; return v.f;
}
__device__ __forceinline__ u16 f2bf(float f) {
    u32 x = __float_as_uint(f);
    u32 r = (x + 0x7fffu + ((x >> 16) & 1u)) >> 16;
    return (u16)r;
}
__device__ __forceinline__ float loadf(const void* p, size_t i, int dt) {
    return dt ? ((const float*)p)[i] : bf2f(((const u16*)p)[i]);
}
__device__ __forceinline__ half8 cvt8_bf16(uint4 v) {
    half8 h;
    h[0] = (f16)bf2f((u16)(v.x & 0xffff)); h[1] = (f16)bf2f((u16)(v.x >> 16));
    h[2] = (f16)bf2f((u16)(v.y & 0xffff)); h[3] = (f16)bf2f((u16)(v.y >> 16));
    h[4] = (f16)bf2f((u16)(v.z & 0xffff)); h[5] = (f16)bf2f((u16)(v.z >> 16));
    h[6] = (f16)bf2f((u16)(v.w & 0xffff)); h[7] = (f16)bf2f((u16)(v.w >> 16));
    return h;
}
__device__ __forceinline__ u64 tagmask(int t) {   // sign-bit tag (h >= 0)
    return ((t & 1) ? 0x0000000000008000ull : 0ull) |
           ((t & 2) ? 0x0000000080000000ull : 0ull) |
           ((t & 4) ? 0x0000800000000000ull : 0ull) |
           ((t & 8) ? 0x8000000000000000ull : 0ull);
}
__device__ __forceinline__ u64 ztag(int t) {      // LSB tag (z signed)
    return ((u64)(t & 1)) | ((u64)((t >> 1) & 1) << 16) |
           ((u64)((t >> 2) & 1) << 32) | ((u64)((t >> 3) & 1) << 48);
}
__device__ __forceinline__ u64 aload(u64* p) {
    return __hip_atomic_load(p, __ATOMIC_RELAXED, __HIP_MEMORY_SCOPE_AGENT);
}
__device__ __forceinline__ void astore(u64* p, u64 v) {
    __hip_atomic_store(p, v, __ATOMIC_RELAXED, __HIP_MEMORY_SCOPE_AGENT);
}
__device__ __forceinline__ u32 aload32(u32* p) {
    return __hip_atomic_load(p, __ATOMIC_RELAXED, __HIP_MEMORY_SCOPE_AGENT);
}
__device__ __forceinline__ void astore32(u32* p, u32 v) {
    __hip_atomic_store(p, v, __ATOMIC_RELAXED, __HIP_MEMORY_SCOPE_AGENT);
}
__device__ __forceinline__ float f16u(u16 b) {
    union { u16 u; f16 h; } c; c.u = b; return (float)c.h;
}
// Scatter one col-major u64 (word = col*4 + quad) into swizzled stage.
__device__ __forceinline__ void scat_store(f16* sbuf, int word, u64 v) {
    int col = word >> 2, q = word & 3;
#pragma unroll
    for (int i = 0; i < 4; ++i) {
        int row = q * 4 + i;
        union { u16 u; f16 h; } c;
        c.u = (u16)(v >> (16 * i));
        sbuf[row * 512 + ((col >> 3) ^ (row & 7)) * 8 + (col & 7)] = c.h;
    }
}

// --------------------------- dtype detection -------------------------------
__global__ void detect_kernel(const u16* __restrict__ xr, int* __restrict__ dtf,
                              u32* __restrict__ progP, u32* __restrict__ progL) {
    int lane = threadIdx.x;
    u16 u0 = xr[(lane * 2 + 0) * 2];
    u16 u1 = xr[(lane * 2 + 1) * 2];
    int e0 = (u0 >> 7) & 0xff, e1 = (u1 >> 7) & 0xff;
    int c0 = (e0 >= 0x60 && e0 <= 0x8f) ? 1 : 0;
    int c1 = (e1 >= 0x60 && e1 <= 0x8f) ? 1 : 0;
    int tot = __popcll(__ballot(c0)) + __popcll(__ballot(c1));
    if (lane == 0) *dtf = (tot >= 96) ? 0 : 1;   // 0 = bf16, 1 = fp32
    progP[lane] = 0;
    progL[lane] = 0;
}

// --------------------------- prep kernels ----------------------------------
__global__ void cvt_w_kernel(const void* __restrict__ in, f16* __restrict__ out,
                             int n, const int* __restrict__ dtf) {
    int dt = *dtf;
    for (int i = blockIdx.x * blockDim.x + threadIdx.x; i < n; i += gridDim.x * blockDim.x)
        out[i] = (f16)loadf(in, i, dt);
}

__global__ void bias_kernel(const void* __restrict__ bi, const void* __restrict__ bh,
                            float* __restrict__ bias, const int* __restrict__ dtf) {
    int dt = *dtf;
    int i = blockIdx.x * blockDim.x + threadIdx.x;
    if (i < H_DIM) bias[i] = loadf(bi, i, dt) + loadf(bh, i, dt);
}

__global__ void fcb_kernel(const void* __restrict__ in, float* __restrict__ out,
                           const int* __restrict__ dtf) {
    int i = threadIdx.x;
    if (i < 128) out[i] = loadf(in, i, *dtf);
}

__global__ void initz_kernel(u64* __restrict__ hexZ) {
    int i = blockIdx.x * blockDim.x + threadIdx.x;   // 65536 threads
    hexZ[i] = 0x0001000100010001ull;                 // LSB tag 15
}

// --------------------------- tiled MFMA GEMM -------------------------------
template<int RAW>
__global__ __launch_bounds__(256)
void gemm_tiled(const void* __restrict__ Araw, const f16* __restrict__ Bw,
                const float* __restrict__ bias, f16* __restrict__ C,
                int lgTc, int t_off, int K, const int* __restrict__ dtf)
{
    __shared__ f16 As[64][40];
    __shared__ f16 Bs[64][40];
    const int dt = RAW ? *dtf : 0;
    const int m0 = blockIdx.x * 64, n0 = blockIdx.y * 64;
    const int tid = threadIdx.x;
    const int wv = tid >> 6, lane = tid & 63;
    const int lr = lane & 15, quad = lane >> 4;
    const int srow = tid >> 2, skq = tid & 3;

    float4v acc[4] = {{0.f,0.f,0.f,0.f},{0.f,0.f,0.f,0.f},{0.f,0.f,0.f,0.f},{0.f,0.f,0.f,0.f}};

    size_t arow;
    {
        int ml = m0 + srow;
        if (RAW) {
            int b = ml >> lgTc, tt = ml & ((1 << lgTc) - 1);
            arow = (size_t)b * T_LEN + t_off + tt;
        } else arow = (size_t)ml;
    }
    const f16* pb = Bw + (size_t)(n0 + srow) * K + skq * 8;

    for (int k0 = 0; k0 < K; k0 += 32) {
        half8 av;
        if (RAW) {
            if (dt) {
                const float* ap = (const float*)Araw + arow * K + k0 + skq * 8;
                float4v f0 = *(const float4v*)ap;
                float4v f1 = *(const float4v*)(ap + 4);
                av[0]=(f16)f0[0]; av[1]=(f16)f0[1]; av[2]=(f16)f0[2]; av[3]=(f16)f0[3];
                av[4]=(f16)f1[0]; av[5]=(f16)f1[1]; av[6]=(f16)f1[2]; av[7]=(f16)f1[3];
            } else {
                av = cvt8_bf16(*(const uint4*)((const u16*)Araw + arow * K + k0 + skq * 8));
            }
        } else {
            av = *(const half8*)((const f16*)Araw + arow * K + k0 + skq * 8);
        }
        half8 bv = *(const half8*)(pb + k0);
        __syncthreads();
        *(half8*)&As[srow][skq * 8] = av;
        *(half8*)&Bs[srow][skq * 8] = bv;
        __syncthreads();
        half8 bf = *(const half8*)&Bs[wv * 16 + lr][quad * 8];
#pragma unroll
        for (int mt = 0; mt < 4; ++mt) {
            half8 af = *(const half8*)&As[mt * 16 + lr][quad * 8];
            acc[mt] = __builtin_amdgcn_mfma_f32_16x16x32_f16(af, bf, acc[mt], 0, 0, 0);
        }
    }
    const int n = n0 + wv * 16 + lr;
    const float bval = bias[n];
#pragma unroll
    for (int mt = 0; mt < 4; ++mt) {
#pragma unroll
        for (int i = 0; i < 4; ++i) {
            int m = m0 + mt * 16 + quad * 4 + i;
            C[(size_t)m * H_DIM + n] = (f16)(acc[mt][i] + bval);
        }
    }
}

// --------------------------- 3-role scan -----------------------------------
// grid = 48 x 256. b<32: c=b&7 -> role=c>>2 (0=L0,1=L1REC), r=c&3, cg=b>>3
// (sibling sets share b%8 -> likely one XCD). b>=32: PROJ, r=(b-32)>>2,
// q=(b-32)&3.
// hex0 [8][4][2048] u64 col-major (sign tags). hex1 [2][4][2048] (sign tags).
// hexZ [8][4][2048] (LSB tags). word = col*4 + quad; u64 = rows q*4..+3.
// progP[r*4+q]: PROJ consumed h0_t -> t+1. progL[r]: value s at top of
// L1REC step s = consumed z_{s-1}.
__global__ __launch_bounds__(256, 1)
void rnn_scan3(const f16* __restrict__ pre0,    // [B,Tc,H] chunk-local
               const f16* __restrict__ Whh0,    // [H,H] fp16
               const f16* __restrict__ Wih1,    // [H,H] fp16
               const f16* __restrict__ Whh1,    // [H,H] fp16
               const float* __restrict__ bias1, // [H] fp32
               u64* __restrict__ hex0,          // [8][4][2048]
               u64* __restrict__ hex1,          // [2][4][2048]
               u64* __restrict__ hexZ,          // [8][4][2048]
               f16* __restrict__ hc0,           // [B,H] layer-0 carry
               f16* __restrict__ hc1,           // [B,H] layer-1 carry
               u32* __restrict__ progP,         // [16 used]
               u32* __restrict__ progL,         // [4 used]
               int t0, int Tc,
               float* __restrict__ h_last)      // [B,H] fp32
{
    __shared__ f16 stage[2][16 * 512];   // recurrent h double buffer
    __shared__ f16 sH0[16 * 512];        // PROJ h0 staging
    const int b = blockIdx.x;
    int role, r, cg;
    if (b < 32) { int c = b & 7; role = c >> 2; r = c & 3; cg = b >> 3; }
    else        { role = 2; r = (b - 32) >> 2; cg = (b - 32) & 3; }
    const int rows0 = r * 16;
    const int tid = threadIdx.x;
    const int w = tid >> 6, lane = tid & 63;
    const int lr = lane & 15, quad = lane >> 4;
    const int c0w = cg * 128 + w * 32;
    const int wbase = tid * 8;                 // consumer: words [wbase,+8)
    const bool mine = (tid >> 6) == cg;        // words' col-group == own

    if (role == 2) {
        // ============================ PROJ ============================
        half8 Bp[2][16];
#pragma unroll
        for (int j = 0; j < 2; ++j)
#pragma unroll
            for (int kc = 0; kc < 16; ++kc)
                Bp[j][kc] = *(const half8*)(Wih1 + (size_t)(c0w + j * 16 + lr) * H_DIM
                                            + kc * 32 + quad * 8);
        float bvv[2] = { bias1[c0w + lr], bias1[c0w + 16 + lr] };
        const int z0 = (c0w + lr) * 4 + quad;

        u64 vv[8];
        {
            u64* src = hex0 + ((size_t)(t0 & 7) * 4 + r) * 2048;
#pragma unroll
            for (int k = 0; k < 8; ++k) vv[k] = aload(&src[wbase + k]);
        }

        for (int tt = 0; tt < Tc; ++tt) {
            const int t = t0 + tt;
            const int nb = t & 7;
            const u64 em = tagmask(t);
            const int need = t - LAG;
            const u32 want = (u32)(need + 1);

            u32 plv = 0xffffffffu;
            if (need >= 0) plv = aload32(&progL[r]);   // early poll

            // [A] validate h0_t (all 8 words) -> sH0
            {
                u64* src = hex0 + ((size_t)nb * 4 + r) * 2048;
                int pend = 0;
#pragma unroll
                for (int k = 0; k < 8; ++k)
                    if ((vv[k] & SGN) != em) pend |= 1 << k;
                int guard = 0;
                while (pend && guard < SPIN_LIM) {
#pragma unroll
                    for (int k = 0; k < 8; ++k)
                        if (pend & (1 << k)) vv[k] = aload(&src[wbase + k]);
#pragma unroll
                    for (int k = 0; k < 8; ++k)
                        if ((pend & (1 << k)) && ((vv[k] & SGN) == em))
                            pend &= ~(1 << k);
                    ++guard;
                }
#pragma unroll
                for (int k = 0; k < 8; ++k)
                    scat_store(sH0, wbase + k, vv[k] & VMASK);
            }
            __syncthreads();   // sH0 ready; all hex0[t] reads done
            if (tid == 0) astore32(&progP[r * 4 + cg], (u32)(t + 1));

            float4v acc0 = {0.f,0.f,0.f,0.f}, acc1 = {0.f,0.f,0.f,0.f};
#pragma unroll
            for (int kc = 0; kc < 16; ++kc) {
                half8 a = *(const half8*)&sH0[lr * 512 + (((kc * 4 + quad) ^ (lr & 7)) * 8)];
                acc0 = __builtin_amdgcn_mfma_f32_16x16x32_f16(a, Bp[0][kc], acc0, 0, 0, 0);
                acc1 = __builtin_amdgcn_mfma_f32_16x16x32_f16(a, Bp[1][kc], acc1, 0, 0, 0);
            }

            // pack z with LSB tags (u64 = rows quad*4..+3 of one col)
            const u64 ez = ztag(t);
            u64 zw[2];
#pragma unroll
            for (int j = 0; j < 2; ++j) {
                const float4v& a = j ? acc1 : acc0;
                u64 wp = 0;
#pragma unroll
                for (int i = 0; i < 4; ++i) {
                    union { f16 h; u16 u; } c;
                    c.h = (f16)(a[i] + bvv[j]);
                    wp |= ((u64)(c.u & 0xFFFEu)) << (16 * i);
                }
                zw[j] = wp | ez;
            }

            // throttle: publishing z_t destroys z_{t-8}; progL>=t-6 certifies.
            if (need >= 0) {
                int g = 0;
                while (plv < want && g < SPIN_LIM) { plv = aload32(&progL[r]); ++g; }
            }
            {
                u64* dz = hexZ + ((size_t)nb * 4 + r) * 2048;
                astore(&dz[z0], zw[0]);
                astore(&dz[z0 + 64], zw[1]);
            }
            if (tt + 1 < Tc) {
                u64* srcn = hex0 + ((size_t)((t + 1) & 7) * 4 + r) * 2048;
#pragma unroll
                for (int k = 0; k < 8; ++k) vv[k] = aload(&srcn[wbase + k]);
            }
            __syncthreads();   // protect sH0 rewrite next iteration
        }
        return;
    }

    // ===================== L0 / L1REC (single-barrier step) =================
    const f16* Wrec = role ? Whh1 : Whh0;
    f16* hcar = role ? hc1 : hc0;
    u64* hexOwn = role ? hex1 : hex0;

    half8 Bf[2][16];
#pragma unroll
    for (int j = 0; j < 2; ++j)
#pragma unroll
        for (int kc = 0; kc < 16; ++kc)
            Bf[j][kc] = *(const half8*)(Wrec + (size_t)(c0w + j * 16 + lr) * H_DIM
                                        + kc * 32 + quad * 8);

    if (t0 > 0) {
        int row = tid >> 4, g0 = (tid & 15) * 4;
#pragma unroll
        for (int gq = 0; gq < 4; ++gq) {
            int g = g0 + gq;
            *(uint4*)&stage[(t0 - 1) & 1][row * 512 + ((g ^ (row & 7)) * 8)] =
                *(const uint4*)(hcar + (size_t)(rows0 + row) * H_DIM + g * 8);
        }
    }
    __syncthreads();

    u64 sv[8];                             // in-flight sibling words (t-1)
    u64 vvz[2];                            // L1REC in-flight z words (t)
    const int z0 = (c0w + lr) * 4 + quad;
    if (role) {
        u64* zb = hexZ + ((size_t)(t0 & 7) * 4 + r) * 2048;
        vvz[0] = aload(&zb[z0]);
        vvz[1] = aload(&zb[z0 + 64]);
    }
    f16 pvh[2][4];                         // L0 pre_t (pipelined)
    if (!role) {
#pragma unroll
        for (int j = 0; j < 2; ++j)
#pragma unroll
            for (int i = 0; i < 4; ++i)
                pvh[j][i] = pre0[((size_t)(rows0 + quad * 4 + i) * Tc + 0) * H_DIM
                                 + c0w + j * 16 + lr];
    }

    for (int tt = 0; tt < Tc; ++tt) {
        const int t = t0 + tt;
        const int p = (t - 1) & 1, np = t & 1;
        const u64 em = tagmask(t);
        const int nbOwn = role ? (t & 1) : (t & 7);
        const int need = t - LAG;
        const u32 want = (u32)(need + 1);

        u32 ppv = 0xffffffffu;
        if (!role && need >= 0 && lane < 4)
            ppv = aload32(&progP[r * 4 + lane]);       // early poll

        // [A] validate sibling words of t-1 -> stage[p]
        if (tt > 0 && !mine) {
            u64* src = hexOwn + ((size_t)(role ? ((t - 1) & 1) : ((t - 1) & 7)) * 4 + r) * 2048;
            const u64 emp = tagmask(t - 1);
            int pend = 0;
#pragma unroll
            for (int k = 0; k < 8; ++k)
                if ((sv[k] & SGN) != emp) pend |= 1 << k;
            int guard = 0;
            while (pend && guard < SPIN_LIM) {
#pragma unroll
                for (int k = 0; k < 8; ++k)
                    if (pend & (1 << k)) sv[k] = aload(&src[wbase + k]);
#pragma unroll
                for (int k = 0; k < 8; ++k)
                    if ((pend & (1 << k)) && ((sv[k] & SGN) == emp))
                        pend &= ~(1 << k);
                ++guard;
            }
#pragma unroll
            for (int k = 0; k < 8; ++k)
                scat_store(stage[p], wbase + k, sv[k] & VMASK);
        }
        __syncthreads();   // stage[p] complete (sib + own-from-[E] of t-1)

        // L1REC: report consumed z_{t-1} (all threads past [D] of t-1).
        if (role && tid == 0) astore32(&progL[r], (u32)t);

        // [D] MFMA K=512 from stage[p].
        float4v acc0 = {0.f,0.f,0.f,0.f}, acc1 = {0.f,0.f,0.f,0.f};
        if (t > 0) {
            const f16* sb = stage[p];
#pragma unroll
            for (int kc = 0; kc < 16; ++kc) {
                half8 a = *(const half8*)&sb[lr * 512 + (((kc * 4 + quad) ^ (lr & 7)) * 8)];
                acc0 = __builtin_amdgcn_mfma_f32_16x16x32_f16(a, Bf[0][kc], acc0, 0, 0, 0);
                acc1 = __builtin_amdgcn_mfma_f32_16x16x32_f16(a, Bf[1][kc], acc1, 0, 0, 0);
            }
        }

        // L1REC: validate z_t (prefetched; PROJ leads -> usually hit).
        if (role) {
            u64* zb = hexZ + ((size_t)(t & 7) * 4 + r) * 2048;
            const u64 ez = ztag(t);
            int pend = 0;
            if ((vvz[0] & ZMASK) != ez) pend |= 1;
            if ((vvz[1] & ZMASK) != ez) pend |= 2;
            int guard = 0;
            while (pend && guard < SPIN_LIM) {
                if (pend & 1) { vvz[0] = aload(&zb[z0]);      if ((vvz[0] & ZMASK) == ez) pend &= ~1; }
                if (pend & 2) { vvz[1] = aload(&zb[z0 + 64]); if ((vvz[1] & ZMASK) == ez) pend &= ~2; }
                ++guard;
            }
        }

        // [E] h_t = relu(acc + pv): publish FIRST (col-major, own words),
        // then stage-own, carry, prefetches. No barrier before publish.
        f16 hv[2][4];
        u64 pw[2];
#pragma unroll
        for (int j = 0; j < 2; ++j) {
            const float4v& a = j ? acc1 : acc0;
            u64 wp = 0;
#pragma unroll
            for (int i = 0; i < 4; ++i) {
                float pvv;
                if (role) pvv = f16u((u16)((vvz[j] >> (16 * i)) & 0xFFFEu));
                else      pvv = (float)pvh[j][i];
                float hval = fmaxf(a[i] + pvv, 0.f);
                hv[j][i] = (f16)hval;
                union { f16 h; u16 u; } c; c.h = hv[j][i];
                wp |= ((u64)c.u) << (16 * i);
            }
            pw[j] = wp | em;
        }
        // L0 throttle (hex0 ring reuse vs PROJ): resolve just before publish.
        if (!role && need >= 0) {
            bool ok = __all((lane < 4) ? (ppv >= want) : 1);
            int g = 0;
            while (!ok && g < SPIN_LIM) {
                if (lane < 4) ppv = aload32(&progP[r * 4 + lane]);
                ok = __all((lane < 4) ? (ppv >= want) : 1);
                ++g;
            }
        }
        {
            u64* dst = hexOwn + ((size_t)nbOwn * 4 + r) * 2048;
            astore(&dst[z0], pw[0]);          // word (c0w+lr)*4+quad
            astore(&dst[z0 + 64], pw[1]);     // word (c0w+16+lr)*4+quad
        }
        // stage own cols into stage[np]
#pragma unroll
        for (int j = 0; j < 2; ++j)
#pragma unroll
            for (int i = 0; i < 4; ++i) {
                int row = quad * 4 + i, lc = c0w + j * 16 + lr;
                stage[np][row * 512 + ((lc >> 3) ^ (row & 7)) * 8 + (lc & 7)] = hv[j][i];
            }
        if (role && h_last && t == T_LEN - 1) {
#pragma unroll
            for (int j = 0; j < 2; ++j)
#pragma unroll
                for (int i = 0; i < 4; ++i)
                    h_last[(size_t)(rows0 + quad * 4 + i) * H_DIM + c0w + j * 16 + lr] =
                        (float)hv[j][i];
        }
        if (tt == Tc - 1) {
#pragma unroll
            for (int j = 0; j < 2; ++j)
#pragma unroll
                for (int i = 0; i < 4; ++i)
                    hcar[(size_t)(rows0 + quad * 4 + i) * H_DIM + c0w + j * 16 + lr] =
                        hv[j][i];
        }
        // issue sibling loads for step t (just published by siblings too)
        if (!mine) {
            u64* src = hexOwn + ((size_t)nbOwn * 4 + r) * 2048;
#pragma unroll
            for (int k = 0; k < 8; ++k) sv[k] = aload(&src[wbase + k]);
        }
        // prefetch next input
        if (tt + 1 < Tc) {
            if (!role) {
#pragma unroll
                for (int j = 0; j < 2; ++j)
#pragma unroll
                    for (int i = 0; i < 4; ++i)
                        pvh[j][i] = pre0[((size_t)(rows0 + quad * 4 + i) * Tc + tt + 1)
                                         * H_DIM + c0w + j * 16 + lr];
            } else {
                u64* zb = hexZ + ((size_t)((t + 1) & 7) * 4 + r) * 2048;
                vvz[0] = aload(&zb[z0]);
                vvz[1] = aload(&zb[z0 + 64]);
            }
        }
        // single barrier lives at top of next iteration ([A] -> barrier)
    }
}

// --------------------------- final FC --------------------------------------
__global__ void fc_kernel(const float* __restrict__ hlast, const f16* __restrict__ fcw,
                          const float* __restrict__ fcb, void* __restrict__ out,
                          const int* __restrict__ dtf) {
    int b = blockIdx.x, c = threadIdx.x;
    const float* hrow = hlast + b * H_DIM;
    const f16* wrow = fcw + (size_t)c * H_DIM;
    float s = fcb[c];
    for (int h0 = 0; h0 < H_DIM; h0 += 8) {
        half8 w = *(const half8*)(wrow + h0);
#pragma unroll
        for (int j = 0; j < 8; ++j) s += hrow[h0 + j] * (float)w[j];
    }
    if (*dtf) ((float*)out)[b * 128 + c] = s;
    else      ((u16*)out)[b * 128 + c] = f2bf(s);
}

// --------------------------- launch ----------------------------------------
extern "C" void kernel_launch(void* const* d_in, const int* in_sizes, int n_in,
                              void* d_out, int out_size, void* d_ws, size_t ws_size,
                              hipStream_t stream)
{
    const void* x     = d_in[0];
    const void* W_ih0 = d_in[1];
    const void* W_hh0 = d_in[2];
    const void* b_ih0 = d_in[3];
    const void* b_hh0 = d_in[4];
    const void* W_ih1 = d_in[5];
    const void* W_hh1 = d_in[6];
    const void* b_ih1 = d_in[7];
    const void* b_hh1 = d_in[8];
    const void* fc_w  = d_in[9];
    const void* fc_b  = d_in[10];

    char* ws = (char*)d_ws;
    int*   dtf   = (int*)(ws + 0);            //     64 B
    float* bias0 = (float*)(ws + 4096);       //   2048 B
    float* bias1 = (float*)(ws + 6144);       //   2048 B
    float* fcbf  = (float*)(ws + 8192);       //    512 B
    u32*   progP = (u32*)(ws + 12288);        //    256 B
    u32*   progL = (u32*)(ws + 12544);        //    256 B
    float* hlast = (float*)(ws + 16384);      // 131072 B
    f16*   hc0   = (f16*)(ws + 147456);       //  65536 B
    f16*   hc1   = (f16*)(ws + 212992);       //  65536 B
    u64*   hex0  = (u64*)(ws + 278528);       // 524288 B [8][4][2048]
    u64*   hex1  = (u64*)(ws + 802816);       // 131072 B [2][4][2048]
    u64*   hexZ  = (u64*)(ws + 933888);       // 524288 B [8][4][2048]
    f16*   Wih0f = (f16*)(ws + 1458176);      // 262144 B
    f16*   Whh0f = (f16*)(ws + 1720320);      // 524288 B
    f16*   Wih1f = (f16*)(ws + 2244608);      // 524288 B
    f16*   Whh1f = (f16*)(ws + 2768896);      // 524288 B
    f16*   fcwf  = (f16*)(ws + 3293184);      // 131072 B (ends 3424256 < 4MB)

    const size_t misc = 4u << 20;
    int Tc = 128;
    {
        auto need = [&](int tc) {
            return misc + (size_t)B_SZ * (size_t)tc * H_DIM * 2;
        };
        if (ws_size >= need(2048)) Tc = 2048;
        else if (ws_size >= need(1024)) Tc = 1024;
        else if (ws_size >= need(512)) Tc = 512;
        else if (ws_size >= need(256)) Tc = 256;
        else Tc = 128;
    }
    int lgTc = 31 - __builtin_clz((unsigned)Tc);
    f16* bufA = (f16*)(ws + misc);

    detect_kernel<<<dim3(1), dim3(64), 0, stream>>>((const u16*)x, dtf, progP, progL);
    initz_kernel<<<dim3(256), dim3(256), 0, stream>>>(hexZ);
    cvt_w_kernel<<<dim3(512), dim3(256), 0, stream>>>(W_ih0, Wih0f, H_DIM * 256, dtf);
    cvt_w_kernel<<<dim3(1024), dim3(256), 0, stream>>>(W_hh0, Whh0f, H_DIM * H_DIM, dtf);
    cvt_w_kernel<<<dim3(1024), dim3(256), 0, stream>>>(W_ih1, Wih1f, H_DIM * H_DIM, dtf);
    cvt_w_kernel<<<dim3(1024), dim3(256), 0, stream>>>(W_hh1, Whh1f, H_DIM * H_DIM, dtf);
    cvt_w_kernel<<<dim3(256), dim3(256), 0, stream>>>(fc_w, fcwf, 128 * H_DIM, dtf);
    bias_kernel<<<dim3(2), dim3(256), 0, stream>>>(b_ih0, b_hh0, bias0, dtf);
    bias_kernel<<<dim3(2), dim3(256), 0, stream>>>(b_ih1, b_hh1, bias1, dtf);
    fcb_kernel<<<dim3(1), dim3(128), 0, stream>>>(fc_b, fcbf, dtf);

    const int NC = T_LEN / Tc;
    const int mblocks = B_SZ * Tc / 64;
    for (int c = 0; c < NC; ++c) {
        const int t0 = c * Tc;
        gemm_tiled<1><<<dim3(mblocks, 8), 256, 0, stream>>>(
            x, Wih0f, bias0, bufA, lgTc, t0, 256, dtf);
        rnn_scan3<<<dim3(48), dim3(256), 0, stream>>>(
            bufA, Whh0f, Wih1f, Whh1f, bias1, hex0, hex1, hexZ, hc0, hc1,
            progP, progL, t0, Tc, hlast);
    }
    fc_kernel<<<dim3(B_SZ), dim3(128), 0, stream>>>(hlast, fcwf, fcbf, d_out, dtf);
}